// Round 4
// baseline (102.520 us; speedup 1.0000x reference)
//
#include <hip/hip_runtime.h>

// Pool_layer: B=4, N=8192, C=256, NEIGHBOR_NUM=4, P=N/4=2048
// Outputs concatenated in d_out: vertices_pool (B,P,3) fp32, feature_map_pool (B,P,C) fp32.
//
// Reference semantics: neighbors of query n = the 4 SMALLEST indices m with
// dist2(n,m) <= r^2 (self forced via zeroed diagonal), padded with first hit.
// dist2 computed in the reference's exact fp32 order (no FMA contraction).
//
// R3 -> R4: straggler waves serial-scanning 8192 candidates at ~900cyc/iter
// (L2 thrashed by feature gathers) dominated. Two-phase fix:
//   A: wave/query scans first 1024 candidates in ONE shot (no serial chain);
//      failures (-3% of queries) append to a worklist in d_ws.
//   B: 256 blocks; each worklist query scanned by a FULL block (32 cand/thread,
//      parallel), LDS+shuffle tournament for 4 smallest, wave-0 gathers.

#define BB 4
#define NN 8192
#define CC 256
#define PP 2048
#define KK 4
#define CH 16            // chunks of 64 -> kernel A scans 1024 candidates
#define WS_IDS 64        // worklist ids start at this int offset in d_ws
#define B_GRID 256

__device__ __forceinline__ float dist_ref(float xn0, float xn1, float xn2, float sqn,
                                          float x0, float x1, float x2) {
    // sq_m = ((x*x)+(y*y))+(z*z); dot likewise; dist = (-2*dot)+sq_n+sq_m
    const float sqm = __fadd_rn(__fadd_rn(__fmul_rn(x0, x0), __fmul_rn(x1, x1)),
                                __fmul_rn(x2, x2));
    const float dot = __fadd_rn(__fadd_rn(__fmul_rn(xn0, x0), __fmul_rn(xn1, x1)),
                                __fmul_rn(xn2, x2));
    return __fadd_rn(__fadd_rn(__fmul_rn(-2.0f, dot), sqn), sqm);
}

__device__ __forceinline__ void gather_maxpool(const float* __restrict__ feat,
                                               int b, int i, int c0, int c1, int c2, int c3,
                                               int lane, float* __restrict__ out_f) {
    const float4 a0 = ((const float4*)(feat + ((size_t)b * NN + c0) * CC))[lane];
    const float4 a1 = ((const float4*)(feat + ((size_t)b * NN + c1) * CC))[lane];
    const float4 a2 = ((const float4*)(feat + ((size_t)b * NN + c2) * CC))[lane];
    const float4 a3 = ((const float4*)(feat + ((size_t)b * NN + c3) * CC))[lane];
    float4 o;
    o.x = fmaxf(fmaxf(a0.x, a1.x), fmaxf(a2.x, a3.x));
    o.y = fmaxf(fmaxf(a0.y, a1.y), fmaxf(a2.y, a3.y));
    o.z = fmaxf(fmaxf(a0.z, a1.z), fmaxf(a2.z, a3.z));
    o.w = fmaxf(fmaxf(a0.w, a1.w), fmaxf(a2.w, a3.w));
    ((float4*)(out_f + ((size_t)b * PP + i) * CC))[lane] = o;
}

// ---------------- Kernel A: fast path, wave per query ----------------
__global__ __launch_bounds__(256) void pool_query_kernel(
    const float* __restrict__ vertices, const float* __restrict__ feat,
    const int* __restrict__ radius_p, const int* __restrict__ sample_idx,
    float* __restrict__ out_v, float* __restrict__ out_f,
    int* __restrict__ worklist) {
    const int wave = threadIdx.x >> 6;
    const int lane = threadIdx.x & 63;
    const int q = blockIdx.x * 4 + wave;   // [0, B*P)
    const int b = q >> 11;                 // q / P
    const int i = q & (PP - 1);            // q % P
    const float* vb = vertices + (size_t)b * NN * 3;

    // issue ALL 48 candidate loads upfront (independent of the query point)
    float px[CH], py[CH], pz[CH];
    #pragma unroll
    for (int c = 0; c < CH; ++c) {
        const int m = c * 64 + lane;
        px[c] = vb[m * 3 + 0];
        py[c] = vb[m * 3 + 1];
        pz[c] = vb[m * 3 + 2];
    }

    const int n = sample_idx[i];
    const float xn0 = vb[n * 3 + 0];
    const float xn1 = vb[n * 3 + 1];
    const float xn2 = vb[n * 3 + 2];
    const float sqn = __fadd_rn(__fadd_rn(__fmul_rn(xn0, xn0), __fmul_rn(xn1, xn1)),
                                __fmul_rn(xn2, xn2));
    const int r = radius_p[0];
    const float r2 = (float)(r * r);

    // vertices_pool gather (all queries, done here)
    if (lane < 3) out_v[((size_t)b * PP + i) * 3 + lane] = vb[n * 3 + lane];

    int c0 = 0, c1 = 0, c2 = 0, c3 = 0, cnt = 0;
    #pragma unroll
    for (int c = 0; c < CH; ++c) {
        const int m = c * 64 + lane;
        const float dist = dist_ref(xn0, xn1, xn2, sqn, px[c], py[c], pz[c]);
        unsigned long long mask = __ballot((m == n) || !(dist > r2));
        while (mask && cnt < KK) {           // wave-uniform scalar pops
            const int v = c * 64 + (__ffsll((unsigned long long)mask) - 1);
            c3 = (cnt == 3) ? v : c3;
            c2 = (cnt == 2) ? v : c2;
            c1 = (cnt == 1) ? v : c1;
            c0 = (cnt == 0) ? v : c0;
            ++cnt;
            mask &= (mask - 1);
        }
    }

    if (cnt >= KK) {
        gather_maxpool(feat, b, i, c0, c1, c2, c3, lane, out_f);
    } else if (lane == 0) {
        const int pos = atomicAdd(worklist, 1);
        worklist[WS_IDS + pos] = q;
    }
}

// ------------- Kernel B: stragglers, one block per query -------------
__global__ __launch_bounds__(256) void pool_straggler_kernel(
    const float* __restrict__ vertices, const float* __restrict__ feat,
    const int* __restrict__ radius_p, const int* __restrict__ sample_idx,
    float* __restrict__ out_f, const int* __restrict__ worklist) {
    __shared__ int s_loc[256 * 4];
    __shared__ int s_g[4];

    const int count = worklist[0];
    const int tid = threadIdx.x;
    const int lane = tid & 63;

    for (int w = blockIdx.x; w < count; w += gridDim.x) {
        const int q = worklist[WS_IDS + w];
        const int b = q >> 11;
        const int i = q & (PP - 1);
        const float* vb = vertices + (size_t)b * NN * 3;
        const int n = sample_idx[i];
        const float xn0 = vb[n * 3 + 0];
        const float xn1 = vb[n * 3 + 1];
        const float xn2 = vb[n * 3 + 2];
        const float sqn = __fadd_rn(__fadd_rn(__fmul_rn(xn0, xn0), __fmul_rn(xn1, xn1)),
                                    __fmul_rn(xn2, xn2));
        const int r = radius_p[0];
        const float r2 = (float)(r * r);

        // each thread scans 32 candidates: m = k*256 + tid (ascending -> its
        // first 4 hits are its 4 smallest). No early exit, no serial chain.
        int l0 = NN, l1 = NN, l2 = NN, l3 = NN, lcnt = 0;
        #pragma unroll
        for (int k = 0; k < NN / 256; ++k) {
            const int m = k * 256 + tid;
            const float dist = dist_ref(xn0, xn1, xn2, sqn,
                                        vb[m * 3 + 0], vb[m * 3 + 1], vb[m * 3 + 2]);
            const bool hit = (m == n) || !(dist > r2);
            if (hit) {
                l3 = (lcnt == 3) ? m : l3;
                l2 = (lcnt == 2) ? m : l2;
                l1 = (lcnt == 1) ? m : l1;
                l0 = (lcnt == 0) ? m : l0;
                ++lcnt;
            }
        }
        s_loc[tid * 4 + 0] = l0;
        s_loc[tid * 4 + 1] = l1;
        s_loc[tid * 4 + 2] = l2;
        s_loc[tid * 4 + 3] = l3;
        __syncthreads();

        // wave 0: tournament over the 1024 entries for the 4 global smallest
        if (tid < 64) {
            int e[16];
            #pragma unroll
            for (int j = 0; j < 16; ++j) e[j] = s_loc[tid * 16 + j];
            int g0, g1, g2, g3;
            #pragma unroll
            for (int round = 0; round < 4; ++round) {
                int m = NN;
                #pragma unroll
                for (int j = 0; j < 16; ++j) m = min(m, e[j]);
                #pragma unroll
                for (int off = 32; off > 0; off >>= 1)
                    m = min(m, __shfl_xor(m, off));
                // m is wave-uniform: the round-th smallest (or NN sentinel)
                if (round == 0) g0 = m;
                if (round == 1) g1 = m;
                if (round == 2) g2 = m;
                if (round == 3) g3 = m;
                #pragma unroll
                for (int j = 0; j < 16; ++j) e[j] = (e[j] == m) ? NN : e[j];
            }
            // pad with first hit (g0 always valid: self-hit)
            g1 = (g1 == NN) ? g0 : g1;
            g2 = (g2 == NN) ? g0 : g2;
            g3 = (g3 == NN) ? g0 : g3;
            gather_maxpool(feat, b, i, g0, g1, g2, g3, lane, out_f);
        }
        __syncthreads();   // s_loc reused next iteration
    }
    (void)s_g;
}

extern "C" void kernel_launch(void* const* d_in, const int* in_sizes, int n_in,
                              void* d_out, int out_size, void* d_ws, size_t ws_size,
                              hipStream_t stream) {
    const float* vertices   = (const float*)d_in[0]; // (B,N,3) fp32
    const float* feat       = (const float*)d_in[1]; // (B,N,C) fp32
    const int*   radius_p   = (const int*)d_in[2];   // scalar int
    const int*   sample_idx = (const int*)d_in[3];   // (P,) int32

    float* out_v = (float*)d_out;                    // (B,P,3)
    float* out_f = out_v + (size_t)BB * PP * 3;      // (B,P,C)
    int*   wl    = (int*)d_ws;                       // [0]=count, [WS_IDS..]=qids

    // zero the worklist counter (becomes a memset node under graph capture)
    hipMemsetAsync(wl, 0, sizeof(int), stream);

    pool_query_kernel<<<dim3(BB * PP / 4), dim3(256), 0, stream>>>(
        vertices, feat, radius_p, sample_idx, out_v, out_f, wl);
    pool_straggler_kernel<<<dim3(B_GRID), dim3(256), 0, stream>>>(
        vertices, feat, radius_p, sample_idx, out_f, wl);
}

// Round 5
// 96.929 us; speedup vs baseline: 1.0577x; 1.0577x over previous
//
#include <hip/hip_runtime.h>

// Pool_layer: B=4, N=8192, C=256, NEIGHBOR_NUM=4, P=N/4=2048
// d_out = vertices_pool (B,P,3) fp32 || feature_map_pool (B,P,C) fp32.
//
// Reference semantics: neighbors of query n = the 4 SMALLEST indices m with
// dist2(n,m) <= r^2 (self forced via zeroed diagonal), padded with first hit.
// dist2 in the reference's exact fp32 order (FMA contraction blocked).
//
// R4 -> R5: multi-dispatch worklist regressed (dispatch overhead + serialized
// straggler kernel). Single dispatch again:
//   stage 1: wave scans first 512 candidates in one shot (24 up-front loads).
//   stage 2 (wave-uniform, ~3-6% of waves): lane-parallel scan of ALL 8192 —
//     each lane keeps its first-4 (ascending) hits; 8 rounds x 48 loads in
//     flight; then a 4-round shfl-min k-way-merge tournament for the global 4.
// Worst-case serial chain: ~9 latency rounds (vs 128 in R1).

#define BB 4
#define NN 8192
#define CC 256
#define PP 2048
#define KK 4
#define CH1 8             // stage 1: 8*64  = 512 candidates, one shot
#define CH2 16            // stage 2: 16*64 = 1024 candidates per round
#define R2ROUNDS (NN / (64 * CH2))   // 8 rounds

__device__ __forceinline__ float dist_ref(float xn0, float xn1, float xn2, float sqn,
                                          float x0, float x1, float x2) {
    // sq_m = ((x*x)+(y*y))+(z*z); dot likewise; dist = (-2*dot)+sq_n+sq_m
    const float sqm = __fadd_rn(__fadd_rn(__fmul_rn(x0, x0), __fmul_rn(x1, x1)),
                                __fmul_rn(x2, x2));
    const float dot = __fadd_rn(__fadd_rn(__fmul_rn(xn0, x0), __fmul_rn(xn1, x1)),
                                __fmul_rn(xn2, x2));
    return __fadd_rn(__fadd_rn(__fmul_rn(-2.0f, dot), sqn), sqm);
}

__global__ __launch_bounds__(256) void pool_layer_kernel(
    const float* __restrict__ vertices,   // (B, N, 3)
    const float* __restrict__ feat,       // (B, N, C)
    const int*   __restrict__ radius_p,   // (1,)
    const int*   __restrict__ sample_idx, // (P,)
    float* __restrict__ out_v,            // (B, P, 3)
    float* __restrict__ out_f)            // (B, P, C)
{
    const int wave = threadIdx.x >> 6;
    const int lane = threadIdx.x & 63;
    const int q    = blockIdx.x * 4 + wave;   // [0, B*P)
    const int b    = q >> 11;                 // q / P
    const int i    = q & (PP - 1);            // q % P
    const float* vb = vertices + (size_t)b * NN * 3;

    // ---- stage-1 candidate loads, all issued before the query chain ----
    float px[CH1], py[CH1], pz[CH1];
    #pragma unroll
    for (int c = 0; c < CH1; ++c) {
        const int m = c * 64 + lane;
        px[c] = vb[m * 3 + 0];
        py[c] = vb[m * 3 + 1];
        pz[c] = vb[m * 3 + 2];
    }

    const int n = sample_idx[i];
    const float xn0 = vb[n * 3 + 0];
    const float xn1 = vb[n * 3 + 1];
    const float xn2 = vb[n * 3 + 2];
    const float sqn = __fadd_rn(__fadd_rn(__fmul_rn(xn0, xn0), __fmul_rn(xn1, xn1)),
                                __fmul_rn(xn2, xn2));
    const int   r  = radius_p[0];
    const float r2 = (float)(r * r);

    // vertices_pool gather
    if (lane < 3) out_v[((size_t)b * PP + i) * 3 + lane] = vb[n * 3 + lane];

    // ---- stage 1: first 512 candidates, one latency round ----
    int c0 = 0, c1 = 0, c2 = 0, c3 = 0, cnt = 0;
    #pragma unroll
    for (int c = 0; c < CH1; ++c) {
        const int m = c * 64 + lane;
        const float dist = dist_ref(xn0, xn1, xn2, sqn, px[c], py[c], pz[c]);
        unsigned long long mask = __ballot((m == n) || !(dist > r2));
        while (mask && cnt < KK) {            // wave-uniform scalar pops
            const int v = c * 64 + (__ffsll(mask) - 1);
            c3 = (cnt == 3) ? v : c3;
            c2 = (cnt == 2) ? v : c2;
            c1 = (cnt == 1) ? v : c1;
            c0 = (cnt == 0) ? v : c0;
            ++cnt;
            mask &= (mask - 1);
        }
    }

    // ---- stage 2 (wave-uniform, rare): lane-parallel full rescan ----
    if (cnt < KK) {
        int l0 = NN, l1 = NN, l2 = NN, l3 = NN, lcnt = 0;
        for (int base = 0; base < NN; base += 64 * CH2) {
            float qx[CH2], qy[CH2], qz[CH2];
            #pragma unroll
            for (int c = 0; c < CH2; ++c) {
                const int m = base + c * 64 + lane;
                qx[c] = vb[m * 3 + 0];
                qy[c] = vb[m * 3 + 1];
                qz[c] = vb[m * 3 + 2];
            }
            #pragma unroll
            for (int c = 0; c < CH2; ++c) {
                const int m = base + c * 64 + lane;
                const float dist = dist_ref(xn0, xn1, xn2, sqn, qx[c], qy[c], qz[c]);
                const bool hit = (m == n) || !(dist > r2);
                if (hit && lcnt < KK) {        // per-lane ascending first-4
                    l3 = (lcnt == 3) ? m : l3;
                    l2 = (lcnt == 2) ? m : l2;
                    l1 = (lcnt == 1) ? m : l1;
                    l0 = (lcnt == 0) ? m : l0;
                    ++lcnt;
                }
            }
        }
        // k-way merge: 4 rounds of min-of-heads + pop-on-match.
        int g[KK];
        #pragma unroll
        for (int round = 0; round < KK; ++round) {
            int mmin = l0;
            #pragma unroll
            for (int off = 32; off > 0; off >>= 1)
                mmin = min(mmin, __shfl_xor(mmin, off));
            g[round] = mmin;                   // wave-uniform
            if (l0 == mmin) { l0 = l1; l1 = l2; l2 = l3; l3 = NN; }
        }
        // pad with first hit (g[0] always valid: self-hit)
        c0 = g[0];
        c1 = (g[1] == NN) ? g[0] : g[1];
        c2 = (g[2] == NN) ? g[0] : g[2];
        c3 = (g[3] == NN) ? g[0] : g[3];
    }

    // ---- max-pool 4 feature rows (64 lanes x float4 = one 1KB row each) ----
    const float4 a0 = ((const float4*)(feat + ((size_t)b * NN + c0) * CC))[lane];
    const float4 a1 = ((const float4*)(feat + ((size_t)b * NN + c1) * CC))[lane];
    const float4 a2 = ((const float4*)(feat + ((size_t)b * NN + c2) * CC))[lane];
    const float4 a3 = ((const float4*)(feat + ((size_t)b * NN + c3) * CC))[lane];
    float4 o;
    o.x = fmaxf(fmaxf(a0.x, a1.x), fmaxf(a2.x, a3.x));
    o.y = fmaxf(fmaxf(a0.y, a1.y), fmaxf(a2.y, a3.y));
    o.z = fmaxf(fmaxf(a0.z, a1.z), fmaxf(a2.z, a3.z));
    o.w = fmaxf(fmaxf(a0.w, a1.w), fmaxf(a2.w, a3.w));
    ((float4*)(out_f + ((size_t)b * PP + i) * CC))[lane] = o;
}

extern "C" void kernel_launch(void* const* d_in, const int* in_sizes, int n_in,
                              void* d_out, int out_size, void* d_ws, size_t ws_size,
                              hipStream_t stream) {
    const float* vertices   = (const float*)d_in[0]; // (B,N,3) fp32
    const float* feat       = (const float*)d_in[1]; // (B,N,C) fp32
    const int*   radius_p   = (const int*)d_in[2];   // scalar int
    const int*   sample_idx = (const int*)d_in[3];   // (P,) int32

    float* out_v = (float*)d_out;                    // (B,P,3)
    float* out_f = out_v + (size_t)BB * PP * 3;      // (B,P,C)

    dim3 grid(BB * PP / 4), block(256);              // 8192 waves, 1 per query
    pool_layer_kernel<<<grid, block, 0, stream>>>(
        vertices, feat, radius_p, sample_idx, out_v, out_f);
}